// Round 1
// baseline (2302.890 us; speedup 1.0000x reference)
//
#include <hip/hip_runtime.h>
#include <hip/hip_bf16.h>

#define DIM 64

static inline int idiv(int a, int b) { return (a + b - 1) / b; }

// ---------------- degrees ----------------
__global__ void k_degrees(const int* __restrict__ row, const int* __restrict__ col,
                          int* __restrict__ dr, int* __restrict__ dc, int E) {
    int e = blockIdx.x * blockDim.x + threadIdx.x;
    if (e < E) {
        atomicAdd(&dr[row[e]], 1);
        atomicAdd(&dc[col[e]], 1);
    }
}

// ---------------- inv sqrt degree ----------------
__global__ void k_inv(const int* __restrict__ dr, const int* __restrict__ dc,
                      float* __restrict__ ir, float* __restrict__ ic, int n) {
    int i = blockIdx.x * blockDim.x + threadIdx.x;
    if (i < n) {
        int a = dr[i], b = dc[i];
        ir[i] = (a > 0) ? rsqrtf((float)a) : 0.f;
        ic[i] = (b > 0) ? rsqrtf((float)b) : 0.f;
    }
}

// ---------------- exclusive scan (single block), ptr[n] = total ----------------
__global__ __launch_bounds__(1024) void k_scan(const int* __restrict__ deg,
                                               int* __restrict__ ptr, int n) {
    __shared__ int sums[1024];
    int t = threadIdx.x;
    int chunk = (n + 1023) >> 10;
    int lo = t * chunk;
    int hi = min(lo + chunk, n);
    int s = 0;
    for (int i = lo; i < hi; i++) s += deg[i];
    sums[t] = s;
    __syncthreads();
    for (int off = 1; off < 1024; off <<= 1) {
        int v = (t >= off) ? sums[t - off] : 0;
        __syncthreads();
        sums[t] += v;
        __syncthreads();
    }
    int run = (t == 0) ? 0 : sums[t - 1];
    for (int i = lo; i < hi; i++) { ptr[i] = run; run += deg[i]; }
    if (t == 1023) ptr[n] = sums[1023];
}

// ---------------- CSR/CSC fill ----------------
__global__ void k_fill(const int* __restrict__ row, const int* __restrict__ col,
                       const int* __restrict__ rptr, const int* __restrict__ cptr,
                       int* __restrict__ cur_r, int* __restrict__ cur_c,
                       int* __restrict__ adj_col, int* __restrict__ adjT_row, int E) {
    int e = blockIdx.x * blockDim.x + threadIdx.x;
    if (e < E) {
        int r = row[e], c = col[e];
        int s1 = atomicAdd(&cur_r[r], 1);
        adj_col[rptr[r] + s1] = c;
        int s2 = atomicAdd(&cur_c[c], 1);
        adjT_row[cptr[c] + s2] = r;
    }
}

// ---------------- SpMM: out[n][d] = inv_self[n] * sum_j inv_nbr[nbr_j] * h[nbr_j][d]
// one 64-lane wave per output row, lane = feature
__global__ __launch_bounds__(256) void k_spmm(const float* __restrict__ h,
                                              float* __restrict__ out,
                                              const int* __restrict__ ptr,
                                              const int* __restrict__ nbr,
                                              const float* __restrict__ inv_self,
                                              const float* __restrict__ inv_nbr, int n) {
    int gw = (blockIdx.x * blockDim.x + threadIdx.x) >> 6;
    int lane = threadIdx.x & 63;
    if (gw >= n) return;
    int beg = ptr[gw], end = ptr[gw + 1];
    float acc = 0.f;
    for (int j0 = beg; j0 < end; j0 += 64) {
        int m = end - j0;
        if (m > 64) m = 64;
        int idx = 0;
        float wv = 0.f;
        if (lane < m) {
            idx = nbr[j0 + lane];
            wv = inv_nbr[idx];
        }
        for (int j = 0; j < m; j++) {
            int c = __shfl(idx, j);
            float w = __shfl(wv, j);
            acc = fmaf(w, h[(size_t)c * DIM + lane], acc);
        }
    }
    out[(size_t)gw * DIM + lane] = inv_self[gw] * acc;
}

// ---------------- GEMM-accumulate: out[n][o] += scale * sum_k h[n][k] * W[o][k]
// lane = output feature o; W row o lives in 64 VGPRs; h[k] broadcast via shfl.
__global__ __launch_bounds__(256) void k_gemm_acc(const float* __restrict__ h,
                                                  const float* __restrict__ W,
                                                  float* __restrict__ out,
                                                  float scale, int n) {
    int lane = threadIdx.x & 63;
    float4 wr[16];
#pragma unroll
    for (int j = 0; j < 16; j++) wr[j] = reinterpret_cast<const float4*>(W)[lane * 16 + j];
    int gw = (blockIdx.x * blockDim.x + threadIdx.x) >> 6;
    int nw = (gridDim.x * blockDim.x) >> 6;
    for (int r = gw; r < n; r += nw) {
        float hreg = h[(size_t)r * DIM + lane];
        float acc = 0.f;
#pragma unroll
        for (int k = 0; k < 64; k++) {
            float hk = __shfl(hreg, k);
            float4 q = wr[k >> 2];
            float w = ((k & 3) == 0) ? q.x : ((k & 3) == 1) ? q.y : ((k & 3) == 2) ? q.z : q.w;
            acc = fmaf(hk, w, acc);
        }
        out[(size_t)r * DIM + lane] += acc * scale;
    }
}

// ---------------- combined bias ----------------
__global__ void k_bias(const float* __restrict__ bs_sd, const float* __restrict__ b0_sd,
                       const float* __restrict__ bs_ds, const float* __restrict__ b0_ds,
                       float* __restrict__ cb) {
    int o = threadIdx.x;  // 64 threads
    float ssd = bs_sd[o] + b0_sd[o];
    float sds = bs_ds[o] + b0_ds[o];
    float sc = 1.f;
    for (int i = 1; i < 4; i++) {
        sc *= 0.5f;
        ssd += bs_sd[i * 64 + o] * sc;
        sds += bs_ds[i * 64 + o] * sc;
    }
    cb[o] = 0.5f * ssd + 0.5f * sds;  // ALPHA = 0.5
}

__global__ void k_addbias(float* __restrict__ out, const float* __restrict__ cb, int total) {
    int i = blockIdx.x * blockDim.x + threadIdx.x;
    if (i < total) out[i] += cb[i & 63];
}

extern "C" void kernel_launch(void* const* d_in, const int* in_sizes, int n_in,
                              void* d_out, int out_size, void* d_ws, size_t ws_size,
                              hipStream_t stream) {
    const float* x     = (const float*)d_in[0];
    const int*   ei    = (const int*)d_in[1];
    const float* Ws_sd = (const float*)d_in[2];
    const float* bs_sd = (const float*)d_in[3];
    const float* Ws_ds = (const float*)d_in[4];
    const float* bs_ds = (const float*)d_in[5];
    const float* W0_sd = (const float*)d_in[6];
    const float* b0_sd = (const float*)d_in[7];
    const float* W0_ds = (const float*)d_in[8];
    const float* b0_ds = (const float*)d_in[9];

    int N = in_sizes[0] / DIM;
    int E = in_sizes[1] / 2;
    const int* row = ei;
    const int* col = ei + E;
    float* out = (float*)d_out;

    // workspace carve-up (64B-aligned chunks)
    char* wsp = (char*)d_ws;
    auto alloc = [&](size_t elems) -> void* {
        void* p = (void*)wsp;
        wsp += ((elems * 4 + 63) / 64) * 64;
        return p;
    };
    int* degs    = (int*)alloc((size_t)4 * N);  // deg_r, deg_c, cur_r, cur_c contiguous
    int* deg_r   = degs;
    int* deg_c   = degs + N;
    int* cur_r   = degs + 2 * (size_t)N;
    int* cur_c   = degs + 3 * (size_t)N;
    int* rptr    = (int*)alloc((size_t)N + 1);
    int* cptr    = (int*)alloc((size_t)N + 1);
    int* adj_col = (int*)alloc((size_t)E);
    int* adjT    = (int*)alloc((size_t)E);
    float* buf0  = (float*)alloc((size_t)N * DIM);
    float* buf1  = (float*)alloc((size_t)N * DIM);
    float* invs  = (float*)alloc((size_t)2 * N);
    float* inv_r = invs;
    float* inv_c = invs + N;
    float* cb    = (float*)alloc(64);

    hipMemsetAsync(degs, 0, (size_t)4 * N * sizeof(int), stream);
    hipMemsetAsync(out, 0, (size_t)N * DIM * sizeof(float), stream);

    k_degrees<<<idiv(E, 256), 256, 0, stream>>>(row, col, deg_r, deg_c, E);
    k_inv<<<idiv(N, 256), 256, 0, stream>>>(deg_r, deg_c, inv_r, inv_c, N);
    k_scan<<<1, 1024, 0, stream>>>(deg_r, rptr, N);
    k_scan<<<1, 1024, 0, stream>>>(deg_c, cptr, N);
    k_fill<<<idiv(E, 256), 256, 0, stream>>>(row, col, rptr, cptr, cur_r, cur_c, adj_col, adjT, E);

    int spmmGrid = idiv(N * 64, 256);  // one wave per row
    int gemmGrid = 2048;

    // hop 0: y0 = A x ; yt0 = A^T x
    k_spmm<<<spmmGrid, 256, 0, stream>>>(x, buf0, rptr, adj_col, inv_r, inv_c, N);
    k_spmm<<<spmmGrid, 256, 0, stream>>>(x, buf1, cptr, adjT, inv_c, inv_r, N);
    k_gemm_acc<<<gemmGrid, 256, 0, stream>>>(buf0, Ws_sd, out, 0.5f, N);
    k_gemm_acc<<<gemmGrid, 256, 0, stream>>>(buf1, Ws_ds, out, 0.5f, N);
    // zero order
    k_gemm_acc<<<gemmGrid, 256, 0, stream>>>(x, W0_sd, out, 0.5f, N);
    k_gemm_acc<<<gemmGrid, 256, 0, stream>>>(x, W0_ds, out, 0.5f, N);

    float* ycur = buf0;   // holds y_{i-1}
    float* yfree = buf1;  // consumed, reusable
    float sc = 1.f;
    for (int i = 1; i < 4; i++) {
        sc *= 0.5f;
        // y_i = A y_{i-1} -> yfree
        k_spmm<<<spmmGrid, 256, 0, stream>>>(ycur, yfree, rptr, adj_col, inv_r, inv_c, N);
        // yt_i = A^T y_i -> old ycur (dead)
        k_spmm<<<spmmGrid, 256, 0, stream>>>(yfree, ycur, cptr, adjT, inv_c, inv_r, N);
        k_gemm_acc<<<gemmGrid, 256, 0, stream>>>(yfree, Ws_sd + (size_t)i * 4096, out, 0.5f * sc, N);
        k_gemm_acc<<<gemmGrid, 256, 0, stream>>>(ycur, Ws_ds + (size_t)i * 4096, out, 0.5f * sc, N);
        float* t = ycur; ycur = yfree; yfree = t;
    }

    k_bias<<<1, 64, 0, stream>>>(bs_sd, b0_sd, bs_ds, b0_ds, cb);
    k_addbias<<<idiv(N * 64, 256), 256, 0, stream>>>(out, cb, N * 64);
}

// Round 2
// 1800.807 us; speedup vs baseline: 1.2788x; 1.2788x over previous
//
#include <hip/hip_runtime.h>
#include <hip/hip_bf16.h>

#define DIM 64

static inline int idiv(int a, int b) { return (a + b - 1) / b; }

// ---------------- degrees ----------------
__global__ void k_degrees(const int* __restrict__ row, const int* __restrict__ col,
                          int* __restrict__ dr, int* __restrict__ dc, int E) {
    int e = blockIdx.x * blockDim.x + threadIdx.x;
    if (e < E) {
        atomicAdd(&dr[row[e]], 1);
        atomicAdd(&dc[col[e]], 1);
    }
}

// ---------------- inv sqrt degree ----------------
__global__ void k_inv(const int* __restrict__ dr, const int* __restrict__ dc,
                      float* __restrict__ ir, float* __restrict__ ic, int n) {
    int i = blockIdx.x * blockDim.x + threadIdx.x;
    if (i < n) {
        int a = dr[i], b = dc[i];
        ir[i] = (a > 0) ? rsqrtf((float)a) : 0.f;
        ic[i] = (b > 0) ? rsqrtf((float)b) : 0.f;
    }
}

// ---------------- exclusive scan: block 0 -> deg_r/rptr, block 1 -> deg_c/cptr ----
__global__ __launch_bounds__(1024) void k_scan2(const int* __restrict__ deg_r,
                                                const int* __restrict__ deg_c,
                                                int* __restrict__ rptr,
                                                int* __restrict__ cptr, int n) {
    const int* deg = (blockIdx.x == 0) ? deg_r : deg_c;
    int* ptr = (blockIdx.x == 0) ? rptr : cptr;
    __shared__ int sums[1024];
    int t = threadIdx.x;
    int chunk = (n + 1023) >> 10;
    int lo = t * chunk;
    int hi = min(lo + chunk, n);
    int s = 0;
    for (int i = lo; i < hi; i++) s += deg[i];
    sums[t] = s;
    __syncthreads();
    for (int off = 1; off < 1024; off <<= 1) {
        int v = (t >= off) ? sums[t - off] : 0;
        __syncthreads();
        sums[t] += v;
        __syncthreads();
    }
    int run = (t == 0) ? 0 : sums[t - 1];
    for (int i = lo; i < hi; i++) { ptr[i] = run; run += deg[i]; }
    if (t == 1023) ptr[n] = sums[1023];
}

// ---------------- CSR/CSC fill ----------------
__global__ void k_fill(const int* __restrict__ row, const int* __restrict__ col,
                       const int* __restrict__ rptr, const int* __restrict__ cptr,
                       int* __restrict__ cur_r, int* __restrict__ cur_c,
                       int* __restrict__ adj_col, int* __restrict__ adjT_row, int E) {
    int e = blockIdx.x * blockDim.x + threadIdx.x;
    if (e < E) {
        int r = row[e], c = col[e];
        int s1 = atomicAdd(&cur_r[r], 1);
        adj_col[rptr[r] + s1] = c;
        int s2 = atomicAdd(&cur_c[c], 1);
        adjT_row[cptr[c] + s2] = r;
    }
}

// ---------------- SpMM: out[n][d] = inv_self[n] * sum_j inv_nbr[nbr_j] * h[nbr_j][d]
// one 64-lane wave per output row, lane = feature. Neighbor index/weight loads
// are wave-uniform (scalar j loop) -> no shuffles, no ds ops in the hot loop.
__global__ __launch_bounds__(256) void k_spmm(const float* __restrict__ h,
                                              float* __restrict__ out,
                                              const int* __restrict__ ptr,
                                              const int* __restrict__ nbr,
                                              const float* __restrict__ inv_self,
                                              const float* __restrict__ inv_nbr, int n) {
    int gw = (blockIdx.x * blockDim.x + threadIdx.x) >> 6;
    int lane = threadIdx.x & 63;
    if (gw >= n) return;
    int beg = ptr[gw], end = ptr[gw + 1];
    float acc = 0.f;
#pragma unroll 4
    for (int j = beg; j < end; j++) {
        int c = nbr[j];           // wave-uniform address -> broadcast load
        float w = inv_nbr[c];     // wave-uniform
        acc = fmaf(w, h[c * DIM + lane], acc);
    }
    out[gw * DIM + lane] = inv_self[gw] * acc;
}

// ---------------- GEMM-accumulate: out[n][o] += scale * sum_k h[n][k] * W[o][k]
__global__ __launch_bounds__(256) void k_gemm_acc(const float* __restrict__ h,
                                                  const float* __restrict__ W,
                                                  float* __restrict__ out,
                                                  float scale, int n) {
    int lane = threadIdx.x & 63;
    float4 wr[16];
#pragma unroll
    for (int j = 0; j < 16; j++) wr[j] = reinterpret_cast<const float4*>(W)[lane * 16 + j];
    int gw = (blockIdx.x * blockDim.x + threadIdx.x) >> 6;
    int nw = (gridDim.x * blockDim.x) >> 6;
    for (int r = gw; r < n; r += nw) {
        float hreg = h[(size_t)r * DIM + lane];
        float acc = 0.f;
#pragma unroll
        for (int k = 0; k < 64; k++) {
            float hk = __shfl(hreg, k);
            float4 q = wr[k >> 2];
            float w = ((k & 3) == 0) ? q.x : ((k & 3) == 1) ? q.y : ((k & 3) == 2) ? q.z : q.w;
            acc = fmaf(hk, w, acc);
        }
        out[(size_t)r * DIM + lane] += acc * scale;
    }
}

// ---------------- combined bias (64 threads) ----------------
__global__ void k_bias(const float* __restrict__ bs_sd, const float* __restrict__ b0_sd,
                       const float* __restrict__ bs_ds, const float* __restrict__ b0_ds,
                       float* __restrict__ cb) {
    int o = threadIdx.x;  // 64 threads
    float ssd = bs_sd[o] + b0_sd[o];
    float sds = bs_ds[o] + b0_ds[o];
    float sc = 1.f;
    for (int i = 1; i < 4; i++) {
        sc *= 0.5f;
        ssd += bs_sd[i * 64 + o] * sc;
        sds += bs_ds[i * 64 + o] * sc;
    }
    cb[o] = 0.5f * ssd + 0.5f * sds;  // ALPHA = 0.5
}

// ---------------- combined zero-order weight: W0c = 0.5*(W0_sd + W0_ds) ----------
__global__ void k_w0(const float* __restrict__ W0_sd, const float* __restrict__ W0_ds,
                     float* __restrict__ W0c) {
    int i = blockIdx.x * blockDim.x + threadIdx.x;
    if (i < 4096) W0c[i] = 0.5f * (W0_sd[i] + W0_ds[i]);
}

// ---------------- init out with broadcast bias ----------------
__global__ void k_init(float* __restrict__ out, const float* __restrict__ cb, int total) {
    int i = blockIdx.x * blockDim.x + threadIdx.x;
    if (i < total) out[i] = cb[i & 63];
}

extern "C" void kernel_launch(void* const* d_in, const int* in_sizes, int n_in,
                              void* d_out, int out_size, void* d_ws, size_t ws_size,
                              hipStream_t stream) {
    const float* x     = (const float*)d_in[0];
    const int*   ei    = (const int*)d_in[1];
    const float* Ws_sd = (const float*)d_in[2];
    const float* bs_sd = (const float*)d_in[3];
    const float* Ws_ds = (const float*)d_in[4];
    const float* bs_ds = (const float*)d_in[5];
    const float* W0_sd = (const float*)d_in[6];
    const float* b0_sd = (const float*)d_in[7];
    const float* W0_ds = (const float*)d_in[8];
    const float* b0_ds = (const float*)d_in[9];

    int N = in_sizes[0] / DIM;
    int E = in_sizes[1] / 2;
    const int* row = ei;
    const int* col = ei + E;
    float* out = (float*)d_out;

    // workspace carve-up (64B-aligned chunks)
    char* wsp = (char*)d_ws;
    auto alloc = [&](size_t elems) -> void* {
        void* p = (void*)wsp;
        wsp += ((elems * 4 + 63) / 64) * 64;
        return p;
    };
    int* degs    = (int*)alloc((size_t)4 * N);  // deg_r, deg_c, cur_r, cur_c contiguous
    int* deg_r   = degs;
    int* deg_c   = degs + N;
    int* cur_r   = degs + 2 * (size_t)N;
    int* cur_c   = degs + 3 * (size_t)N;
    int* rptr    = (int*)alloc((size_t)N + 1);
    int* cptr    = (int*)alloc((size_t)N + 1);
    int* adj_col = (int*)alloc((size_t)E);
    int* adjT    = (int*)alloc((size_t)E);
    float* buf0  = (float*)alloc((size_t)N * DIM);
    float* buf1  = (float*)alloc((size_t)N * DIM);
    float* invs  = (float*)alloc((size_t)2 * N);
    float* inv_r = invs;
    float* inv_c = invs + N;
    float* cb    = (float*)alloc(64);
    float* W0c   = (float*)alloc(4096);

    hipMemsetAsync(degs, 0, (size_t)4 * N * sizeof(int), stream);

    k_degrees<<<idiv(E, 256), 256, 0, stream>>>(row, col, deg_r, deg_c, E);
    k_inv<<<idiv(N, 256), 256, 0, stream>>>(deg_r, deg_c, inv_r, inv_c, N);
    k_scan2<<<2, 1024, 0, stream>>>(deg_r, deg_c, rptr, cptr, N);
    k_fill<<<idiv(E, 256), 256, 0, stream>>>(row, col, rptr, cptr, cur_r, cur_c, adj_col, adjT, E);

    k_bias<<<1, 64, 0, stream>>>(bs_sd, b0_sd, bs_ds, b0_ds, cb);
    k_w0<<<16, 256, 0, stream>>>(W0_sd, W0_ds, W0c);
    k_init<<<idiv(N * 64, 256), 256, 0, stream>>>(out, cb, N * 64);

    int spmmGrid = idiv(N * 64, 256);  // one wave per row
    int gemmGrid = 2048;

    // hop 0: y0 = A x ; yt0 = A^T x
    k_spmm<<<spmmGrid, 256, 0, stream>>>(x, buf0, rptr, adj_col, inv_r, inv_c, N);
    k_spmm<<<spmmGrid, 256, 0, stream>>>(x, buf1, cptr, adjT, inv_c, inv_r, N);
    k_gemm_acc<<<gemmGrid, 256, 0, stream>>>(buf0, Ws_sd, out, 0.5f, N);
    k_gemm_acc<<<gemmGrid, 256, 0, stream>>>(buf1, Ws_ds, out, 0.5f, N);
    // zero order (combined sd+ds weight)
    k_gemm_acc<<<gemmGrid, 256, 0, stream>>>(x, W0c, out, 1.0f, N);

    float* ycur = buf0;   // holds y_{i-1}
    float* yfree = buf1;  // consumed, reusable
    float sc = 1.f;
    for (int i = 1; i < 4; i++) {
        sc *= 0.5f;
        // y_i = A y_{i-1} -> yfree
        k_spmm<<<spmmGrid, 256, 0, stream>>>(ycur, yfree, rptr, adj_col, inv_r, inv_c, N);
        // yt_i = A^T y_i -> old ycur (dead)
        k_spmm<<<spmmGrid, 256, 0, stream>>>(yfree, ycur, cptr, adjT, inv_c, inv_r, N);
        k_gemm_acc<<<gemmGrid, 256, 0, stream>>>(yfree, Ws_sd + (size_t)i * 4096, out, 0.5f * sc, N);
        k_gemm_acc<<<gemmGrid, 256, 0, stream>>>(ycur, Ws_ds + (size_t)i * 4096, out, 0.5f * sc, N);
        float* t = ycur; ycur = yfree; yfree = t;
    }
}

// Round 3
// 1752.293 us; speedup vs baseline: 1.3142x; 1.0277x over previous
//
#include <hip/hip_runtime.h>
#include <hip/hip_bf16.h>

#define DIM 64

static inline int idiv(int a, int b) { return (a + b - 1) / b; }

// ---------------- degrees + slot reservation ----------------
__global__ void k_degrees(const int* __restrict__ row, const int* __restrict__ col,
                          int* __restrict__ dr, int* __restrict__ dc,
                          int* __restrict__ slot_r, int* __restrict__ slot_c, int E) {
    int e = blockIdx.x * blockDim.x + threadIdx.x;
    if (e < E) {
        slot_r[e] = atomicAdd(&dr[row[e]], 1);
        slot_c[e] = atomicAdd(&dc[col[e]], 1);
    }
}

// ---------------- combined prep ----------------
// block 0: exclusive scan deg_r -> rptr, inv_r = rsqrt(deg_r)
// block 1: exclusive scan deg_c -> cptr, inv_c = rsqrt(deg_c)
// block 2: combined bias cb
// block 3: combined zero-order weight W0c
__global__ __launch_bounds__(1024) void k_prep(const int* __restrict__ deg_r,
                                               const int* __restrict__ deg_c,
                                               int* __restrict__ rptr, int* __restrict__ cptr,
                                               float* __restrict__ inv_r, float* __restrict__ inv_c,
                                               int n,
                                               const float* __restrict__ bs_sd, const float* __restrict__ b0_sd,
                                               const float* __restrict__ bs_ds, const float* __restrict__ b0_ds,
                                               float* __restrict__ cb,
                                               const float* __restrict__ W0_sd, const float* __restrict__ W0_ds,
                                               float* __restrict__ W0c) {
    int t = threadIdx.x;
    if (blockIdx.x >= 2) {
        if (blockIdx.x == 2) {
            if (t < 64) {
                float ssd = bs_sd[t] + b0_sd[t];
                float sds = bs_ds[t] + b0_ds[t];
                float sc = 1.f;
                for (int i = 1; i < 4; i++) {
                    sc *= 0.5f;
                    ssd += bs_sd[i * 64 + t] * sc;
                    sds += bs_ds[i * 64 + t] * sc;
                }
                cb[t] = 0.5f * ssd + 0.5f * sds;  // ALPHA = 0.5
            }
        } else {
            for (int i = t; i < 4096; i += 1024) W0c[i] = 0.5f * (W0_sd[i] + W0_ds[i]);
        }
        return;
    }
    const int* deg = (blockIdx.x == 0) ? deg_r : deg_c;
    int* ptr = (blockIdx.x == 0) ? rptr : cptr;
    float* inv = (blockIdx.x == 0) ? inv_r : inv_c;
    __shared__ int sums[1024];
    int chunk = (n + 1023) >> 10;
    int lo = t * chunk;
    int hi = min(lo + chunk, n);
    int s = 0;
    for (int i = lo; i < hi; i++) s += deg[i];
    sums[t] = s;
    __syncthreads();
    for (int off = 1; off < 1024; off <<= 1) {
        int v = (t >= off) ? sums[t - off] : 0;
        __syncthreads();
        sums[t] += v;
        __syncthreads();
    }
    int run = (t == 0) ? 0 : sums[t - 1];
    for (int i = lo; i < hi; i++) {
        int d = deg[i];
        ptr[i] = run;
        inv[i] = (d > 0) ? rsqrtf((float)d) : 0.f;
        run += d;
    }
    if (t == 1023) ptr[n] = sums[1023];
}

// ---------------- CSR/CSC fill (atomic-free, packed idx+weight) ----------------
__global__ void k_fill(const int* __restrict__ row, const int* __restrict__ col,
                       const int* __restrict__ rptr, const int* __restrict__ cptr,
                       const int* __restrict__ slot_r, const int* __restrict__ slot_c,
                       const float* __restrict__ inv_r, const float* __restrict__ inv_c,
                       int2* __restrict__ adj, int2* __restrict__ adjT, int E) {
    int e = blockIdx.x * blockDim.x + threadIdx.x;
    if (e < E) {
        int r = row[e], c = col[e];
        adj[rptr[r] + slot_r[e]] = make_int2(c, __float_as_int(inv_c[c]));
        adjT[cptr[c] + slot_c[e]] = make_int2(r, __float_as_int(inv_r[r]));
    }
}

// ---------------- SpMM: out[n][d] = inv_self[n] * sum_j w_j * h[c_j][d]
// one wave per row, lane = feature; packed (c,w) edges -> single sequential
// 8B load per neighbor, then one independent 256B gather. unroll 8 for MLP.
__global__ __launch_bounds__(256) void k_spmm(const float* __restrict__ h,
                                              float* __restrict__ out,
                                              const int* __restrict__ ptr,
                                              const int2* __restrict__ adj,
                                              const float* __restrict__ inv_self, int n) {
    int gw = (blockIdx.x * blockDim.x + threadIdx.x) >> 6;
    int lane = threadIdx.x & 63;
    if (gw >= n) return;
    int beg = ptr[gw], end = ptr[gw + 1];
    float acc = 0.f;
#pragma unroll 8
    for (int j = beg; j < end; j++) {
        int2 e = adj[j];
        acc = fmaf(__int_as_float(e.y), h[e.x * DIM + lane], acc);
    }
    out[gw * DIM + lane] = inv_self[gw] * acc;
}

// ---------------- single GEMM-accumulate: out[n][o] += scale * (W h)[n][o] ------
__global__ __launch_bounds__(256) void k_gemm_acc(const float* __restrict__ h,
                                                  const float* __restrict__ W,
                                                  float* __restrict__ out,
                                                  float scale, int n) {
    int lane = threadIdx.x & 63;
    float4 wr[16];
#pragma unroll
    for (int j = 0; j < 16; j++) wr[j] = reinterpret_cast<const float4*>(W)[lane * 16 + j];
    int gw = (blockIdx.x * blockDim.x + threadIdx.x) >> 6;
    int nw = (gridDim.x * blockDim.x) >> 6;
    for (int r = gw; r < n; r += nw) {
        float hreg = h[(size_t)r * DIM + lane];
        float acc = 0.f;
#pragma unroll
        for (int k = 0; k < 64; k++) {
            float hk = __shfl(hreg, k);
            float4 q = wr[k >> 2];
            float w = ((k & 3) == 0) ? q.x : ((k & 3) == 1) ? q.y : ((k & 3) == 2) ? q.z : q.w;
            acc = fmaf(hk, w, acc);
        }
        out[(size_t)r * DIM + lane] += acc * scale;
    }
}

// ---------------- fused pair GEMM: out (=|+=) bias? + scale*(Wa ha + Wb hb) ------
template <bool INIT>
__global__ __launch_bounds__(256) void k_gemm2(const float* __restrict__ ha,
                                               const float* __restrict__ Wa,
                                               const float* __restrict__ hb,
                                               const float* __restrict__ Wb,
                                               const float* __restrict__ cb,
                                               float* __restrict__ out,
                                               float scale, int n) {
    int lane = threadIdx.x & 63;
    float4 wa[16], wb[16];
#pragma unroll
    for (int j = 0; j < 16; j++) {
        wa[j] = reinterpret_cast<const float4*>(Wa)[lane * 16 + j];
        wb[j] = reinterpret_cast<const float4*>(Wb)[lane * 16 + j];
    }
    float bias = INIT ? cb[lane] : 0.f;
    int gw = (blockIdx.x * blockDim.x + threadIdx.x) >> 6;
    int nw = (gridDim.x * blockDim.x) >> 6;
    for (int r = gw; r < n; r += nw) {
        float hra = ha[(size_t)r * DIM + lane];
        float hrb = hb[(size_t)r * DIM + lane];
        float acca = 0.f, accb = 0.f;
#pragma unroll
        for (int k = 0; k < 64; k++) {
            float hak = __shfl(hra, k);
            float hbk = __shfl(hrb, k);
            float4 qa = wa[k >> 2];
            float4 qb = wb[k >> 2];
            float wav = ((k & 3) == 0) ? qa.x : ((k & 3) == 1) ? qa.y : ((k & 3) == 2) ? qa.z : qa.w;
            float wbv = ((k & 3) == 0) ? qb.x : ((k & 3) == 1) ? qb.y : ((k & 3) == 2) ? qb.z : qb.w;
            acca = fmaf(hak, wav, acca);
            accb = fmaf(hbk, wbv, accb);
        }
        float v = scale * (acca + accb);
        size_t o = (size_t)r * DIM + lane;
        out[o] = INIT ? (bias + v) : (out[o] + v);
    }
}

extern "C" void kernel_launch(void* const* d_in, const int* in_sizes, int n_in,
                              void* d_out, int out_size, void* d_ws, size_t ws_size,
                              hipStream_t stream) {
    const float* x     = (const float*)d_in[0];
    const int*   ei    = (const int*)d_in[1];
    const float* Ws_sd = (const float*)d_in[2];
    const float* bs_sd = (const float*)d_in[3];
    const float* Ws_ds = (const float*)d_in[4];
    const float* bs_ds = (const float*)d_in[5];
    const float* W0_sd = (const float*)d_in[6];
    const float* b0_sd = (const float*)d_in[7];
    const float* W0_ds = (const float*)d_in[8];
    const float* b0_ds = (const float*)d_in[9];

    int N = in_sizes[0] / DIM;
    int E = in_sizes[1] / 2;
    const int* row = ei;
    const int* col = ei + E;
    float* out = (float*)d_out;

    // workspace carve-up (64B-aligned chunks)
    char* wsp = (char*)d_ws;
    auto alloc = [&](size_t elems) -> void* {
        void* p = (void*)wsp;
        wsp += ((elems * 4 + 63) / 64) * 64;
        return p;
    };
    int* degs   = (int*)alloc((size_t)2 * N);  // deg_r, deg_c
    int* deg_r  = degs;
    int* deg_c  = degs + N;
    int* rptr   = (int*)alloc((size_t)N + 1);
    int* cptr   = (int*)alloc((size_t)N + 1);
    int2* adj   = (int2*)alloc((size_t)2 * E);
    int2* adjT  = (int2*)alloc((size_t)2 * E);
    float* buf0 = (float*)alloc((size_t)N * DIM);
    float* buf1 = (float*)alloc((size_t)N * DIM);
    float* invs = (float*)alloc((size_t)2 * N);
    float* inv_r = invs;
    float* inv_c = invs + N;
    float* cb   = (float*)alloc(64);
    float* W0c  = (float*)alloc(4096);

    // slot arrays alias buf0 (buf0 first written after k_fill completes)
    int* slot_r = (int*)buf0;
    int* slot_c = slot_r + E;  // 2*E ints = 12.8 MB <= 25.6 MB of buf0

    hipMemsetAsync(degs, 0, (size_t)2 * N * sizeof(int), stream);

    k_degrees<<<idiv(E, 256), 256, 0, stream>>>(row, col, deg_r, deg_c, slot_r, slot_c, E);
    k_prep<<<4, 1024, 0, stream>>>(deg_r, deg_c, rptr, cptr, inv_r, inv_c, N,
                                   bs_sd, b0_sd, bs_ds, b0_ds, cb, W0_sd, W0_ds, W0c);
    k_fill<<<idiv(E, 256), 256, 0, stream>>>(row, col, rptr, cptr, slot_r, slot_c,
                                             inv_r, inv_c, adj, adjT, E);

    int spmmGrid = idiv(N * 64, 256);  // one wave per row
    int gemmGrid = 2048;

    // hop 0: y0 = A x ; yt0 = A^T x
    k_spmm<<<spmmGrid, 256, 0, stream>>>(x, buf0, rptr, adj, inv_r, N);
    k_spmm<<<spmmGrid, 256, 0, stream>>>(x, buf1, cptr, adjT, inv_c, N);
    // out = cb + 0.5*(Ws_sd0 y0 + Ws_ds0 yt0)
    k_gemm2<true><<<gemmGrid, 256, 0, stream>>>(buf0, Ws_sd, buf1, Ws_ds, cb, out, 0.5f, N);
    // out += W0c x   (W0c = 0.5*(W0_sd + W0_ds))
    k_gemm_acc<<<gemmGrid, 256, 0, stream>>>(x, W0c, out, 1.0f, N);

    float* ycur = buf0;   // holds y_{i-1}
    float* yfree = buf1;  // consumed, reusable
    float sc = 1.f;
    for (int i = 1; i < 4; i++) {
        sc *= 0.5f;
        // y_i = A y_{i-1} -> yfree ;  yt_i = A^T y_i -> old ycur (dead)
        k_spmm<<<spmmGrid, 256, 0, stream>>>(ycur, yfree, rptr, adj, inv_r, N);
        k_spmm<<<spmmGrid, 256, 0, stream>>>(yfree, ycur, cptr, adjT, inv_c, N);
        // out += 0.5*sc*(Ws_sd[i] y_i + Ws_ds[i] yt_i)
        k_gemm2<false><<<gemmGrid, 256, 0, stream>>>(yfree, Ws_sd + (size_t)i * 4096,
                                                     ycur, Ws_ds + (size_t)i * 4096,
                                                     nullptr, out, 0.5f * sc, N);
        float* t = ycur; ycur = yfree; yfree = t;
    }
}

// Round 4
// 1505.777 us; speedup vs baseline: 1.5294x; 1.1637x over previous
//
#include <hip/hip_runtime.h>
#include <hip/hip_bf16.h>

#define DIM 64
#define SCAN_CHUNK 2048

static inline int idiv(int a, int b) { return (a + b - 1) / b; }

__device__ inline unsigned short f2b(float f) {
    __hip_bfloat16 h = __float2bfloat16(f);
    return *reinterpret_cast<unsigned short*>(&h);
}
__device__ inline float b2f(unsigned short u) {
    __hip_bfloat16 h;
    *reinterpret_cast<unsigned short*>(&h) = u;
    return __bfloat162float(h);
}

// ---------------- degrees + slot reservation ----------------
__global__ void k_degrees(const int* __restrict__ row, const int* __restrict__ col,
                          int* __restrict__ dr, int* __restrict__ dc,
                          int* __restrict__ slot_r, int* __restrict__ slot_c, int E) {
    int e = blockIdx.x * blockDim.x + threadIdx.x;
    if (e < E) {
        slot_r[e] = atomicAdd(&dr[row[e]], 1);
        slot_c[e] = atomicAdd(&dc[col[e]], 1);
    }
}

// ---------------- scan phase A: per-block partial sums ----------------
__global__ __launch_bounds__(256) void k_scan_blk(const int* __restrict__ deg_r,
                                                  const int* __restrict__ deg_c,
                                                  int* __restrict__ part, int n, int G) {
    int b = blockIdx.x;
    const int* deg = (b < G) ? deg_r : deg_c;
    int lb = (b < G) ? b : b - G;
    int base = lb * SCAN_CHUNK;
    int t = threadIdx.x;
    int s = 0;
    for (int i = t; i < SCAN_CHUNK; i += 256) {
        int g = base + i;
        if (g < n) s += deg[g];
    }
    __shared__ int red[256];
    red[t] = s;
    __syncthreads();
    for (int off = 128; off > 0; off >>= 1) {
        if (t < off) red[t] += red[t + off];
        __syncthreads();
    }
    if (t == 0) part[b] = red[0];
}

// ---------------- scan phase B: top scan (+ bias/W0 prep in spare blocks) -------
__global__ __launch_bounds__(1024) void k_scan_top(int* __restrict__ part, int G,
        const float* __restrict__ bs_sd, const float* __restrict__ b0_sd,
        const float* __restrict__ bs_ds, const float* __restrict__ b0_ds,
        float* __restrict__ cb,
        const float* __restrict__ W0_sd, const float* __restrict__ W0_ds,
        float* __restrict__ W0c) {
    int t = threadIdx.x;
    if (blockIdx.x == 2) {
        if (t < 64) {
            float ssd = bs_sd[t] + b0_sd[t];
            float sds = bs_ds[t] + b0_ds[t];
            float sc = 1.f;
            for (int i = 1; i < 4; i++) {
                sc *= 0.5f;
                ssd += bs_sd[i * 64 + t] * sc;
                sds += bs_ds[i * 64 + t] * sc;
            }
            cb[t] = 0.5f * ssd + 0.5f * sds;  // ALPHA = 0.5
        }
        return;
    }
    if (blockIdx.x == 3) {
        for (int i = t; i < 4096; i += 1024) W0c[i] = 0.5f * (W0_sd[i] + W0_ds[i]);
        return;
    }
    int* p = part + ((blockIdx.x == 0) ? 0 : G);
    __shared__ int sums[1024];
    sums[t] = (t < G) ? p[t] : 0;
    __syncthreads();
    for (int off = 1; off < 1024; off <<= 1) {
        int v = (t >= off) ? sums[t - off] : 0;
        __syncthreads();
        sums[t] += v;
        __syncthreads();
    }
    if (t < G) p[t] = (t == 0) ? 0 : sums[t - 1];
}

// ---------------- scan phase C: finish — write ptr + inv ----------------
__global__ __launch_bounds__(256) void k_scan_fin(const int* __restrict__ deg_r,
                                                  const int* __restrict__ deg_c,
                                                  const int* __restrict__ part,
                                                  int* __restrict__ rptr, int* __restrict__ cptr,
                                                  float* __restrict__ inv_r, float* __restrict__ inv_c,
                                                  int n, int G) {
    int b = blockIdx.x;
    bool isr = (b < G);
    const int* deg = isr ? deg_r : deg_c;
    int* ptr = isr ? rptr : cptr;
    float* inv = isr ? inv_r : inv_c;
    int lb = isr ? b : b - G;
    int off = part[b];
    int base = lb * SCAN_CHUNK;
    int t = threadIdx.x;
    int start = base + t * 8;
    int v[8];
    int s = 0;
#pragma unroll
    for (int k = 0; k < 8; k++) {
        int g = start + k;
        int d = (g < n) ? deg[g] : 0;
        v[k] = d;
        s += d;
    }
    __shared__ int sums[256];
    sums[t] = s;
    __syncthreads();
    for (int o = 1; o < 256; o <<= 1) {
        int x = (t >= o) ? sums[t - o] : 0;
        __syncthreads();
        sums[t] += x;
        __syncthreads();
    }
    int run = off + ((t == 0) ? 0 : sums[t - 1]);
#pragma unroll
    for (int k = 0; k < 8; k++) {
        int g = start + k;
        if (g < n) {
            ptr[g] = run;
            inv[g] = (v[k] > 0) ? rsqrtf((float)v[k]) : 0.f;
            run += v[k];
        }
    }
    if (t == 255 && lb == G - 1) ptr[n] = run;  // grand total
}

// ---------------- CSR/CSC fill (atomic-free, packed idx+weight) ----------------
__global__ void k_fill(const int* __restrict__ row, const int* __restrict__ col,
                       const int* __restrict__ rptr, const int* __restrict__ cptr,
                       const int* __restrict__ slot_r, const int* __restrict__ slot_c,
                       const float* __restrict__ inv_r, const float* __restrict__ inv_c,
                       int2* __restrict__ adj, int2* __restrict__ adjT, int E) {
    int e = blockIdx.x * blockDim.x + threadIdx.x;
    if (e < E) {
        int r = row[e], c = col[e];
        adj[rptr[r] + slot_r[e]] = make_int2(c, __float_as_int(inv_c[c]));
        adjT[cptr[c] + slot_c[e]] = make_int2(r, __float_as_int(inv_r[r]));
    }
}

// ---------------- x -> bf16 cast ----------------
__global__ void k_xcast(const float* __restrict__ x, unsigned short* __restrict__ xb, int total) {
    int i = (blockIdx.x * blockDim.x + threadIdx.x) * 4;
    if (i < total) {
        float4 v = *reinterpret_cast<const float4*>(x + i);
        ushort4 o;
        o.x = f2b(v.x); o.y = f2b(v.y); o.z = f2b(v.z); o.w = f2b(v.w);
        *reinterpret_cast<ushort4*>(xb + i) = o;
    }
}

// ---------------- SpMM (bf16 h, bf16 out, fp32 accum) ----------------
// one wave per row, lane = feature; packed (c,w) edges. bf16 row gather = 128B
// = 2 cache lines (vs 4 for fp32) -> half the line fills on the MLP-limited path.
__global__ __launch_bounds__(256) void k_spmm(const unsigned short* __restrict__ h,
                                              unsigned short* __restrict__ out,
                                              const int* __restrict__ ptr,
                                              const int2* __restrict__ adj,
                                              const float* __restrict__ inv_self, int n) {
    int gw = (blockIdx.x * blockDim.x + threadIdx.x) >> 6;
    int lane = threadIdx.x & 63;
    if (gw >= n) return;
    int beg = ptr[gw], end = ptr[gw + 1];
    float acc = 0.f;
#pragma unroll 8
    for (int j = beg; j < end; j++) {
        int2 e = adj[j];
        acc = fmaf(__int_as_float(e.y), b2f(h[e.x * DIM + lane]), acc);
    }
    out[gw * DIM + lane] = f2b(inv_self[gw] * acc);
}

// ---------------- zero-order GEMM (fp32 x): out += (W0c x)[n][o] ----------------
__global__ __launch_bounds__(256) void k_gemm_acc(const float* __restrict__ h,
                                                  const float* __restrict__ W,
                                                  float* __restrict__ out, int n) {
    int lane = threadIdx.x & 63;
    float4 wr[16];
#pragma unroll
    for (int j = 0; j < 16; j++) wr[j] = reinterpret_cast<const float4*>(W)[lane * 16 + j];
    int gw = (blockIdx.x * blockDim.x + threadIdx.x) >> 6;
    int nw = (gridDim.x * blockDim.x) >> 6;
    for (int r = gw; r < n; r += nw) {
        float hreg = h[(size_t)r * DIM + lane];
        float acc = 0.f;
#pragma unroll
        for (int k = 0; k < 64; k++) {
            float hk = __shfl(hreg, k);
            float4 q = wr[k >> 2];
            float w = ((k & 3) == 0) ? q.x : ((k & 3) == 1) ? q.y : ((k & 3) == 2) ? q.z : q.w;
            acc = fmaf(hk, w, acc);
        }
        out[(size_t)r * DIM + lane] += acc;
    }
}

// ---------------- fused pair GEMM (bf16 inputs): out (=|+=) bias? + s*(Wa ha + Wb hb)
template <bool INIT>
__global__ __launch_bounds__(256) void k_gemm2(const unsigned short* __restrict__ ha,
                                               const float* __restrict__ Wa,
                                               const unsigned short* __restrict__ hb,
                                               const float* __restrict__ Wb,
                                               const float* __restrict__ cb,
                                               float* __restrict__ out,
                                               float scale, int n) {
    int lane = threadIdx.x & 63;
    float4 wa[16], wb[16];
#pragma unroll
    for (int j = 0; j < 16; j++) {
        wa[j] = reinterpret_cast<const float4*>(Wa)[lane * 16 + j];
        wb[j] = reinterpret_cast<const float4*>(Wb)[lane * 16 + j];
    }
    float bias = INIT ? cb[lane] : 0.f;
    int gw = (blockIdx.x * blockDim.x + threadIdx.x) >> 6;
    int nw = (gridDim.x * blockDim.x) >> 6;
    for (int r = gw; r < n; r += nw) {
        float hra = b2f(ha[(size_t)r * DIM + lane]);
        float hrb = b2f(hb[(size_t)r * DIM + lane]);
        float acca = 0.f, accb = 0.f;
#pragma unroll
        for (int k = 0; k < 64; k++) {
            float hak = __shfl(hra, k);
            float hbk = __shfl(hrb, k);
            float4 qa = wa[k >> 2];
            float4 qb = wb[k >> 2];
            float wav = ((k & 3) == 0) ? qa.x : ((k & 3) == 1) ? qa.y : ((k & 3) == 2) ? qa.z : qa.w;
            float wbv = ((k & 3) == 0) ? qb.x : ((k & 3) == 1) ? qb.y : ((k & 3) == 2) ? qb.z : qb.w;
            acca = fmaf(hak, wav, acca);
            accb = fmaf(hbk, wbv, accb);
        }
        float v = scale * (acca + accb);
        size_t o = (size_t)r * DIM + lane;
        out[o] = INIT ? (bias + v) : (out[o] + v);
    }
}

extern "C" void kernel_launch(void* const* d_in, const int* in_sizes, int n_in,
                              void* d_out, int out_size, void* d_ws, size_t ws_size,
                              hipStream_t stream) {
    const float* x     = (const float*)d_in[0];
    const int*   ei    = (const int*)d_in[1];
    const float* Ws_sd = (const float*)d_in[2];
    const float* bs_sd = (const float*)d_in[3];
    const float* Ws_ds = (const float*)d_in[4];
    const float* bs_ds = (const float*)d_in[5];
    const float* W0_sd = (const float*)d_in[6];
    const float* b0_sd = (const float*)d_in[7];
    const float* W0_ds = (const float*)d_in[8];
    const float* b0_ds = (const float*)d_in[9];

    int N = in_sizes[0] / DIM;
    int E = in_sizes[1] / 2;
    const int* row = ei;
    const int* col = ei + E;
    float* out = (float*)d_out;

    int G = idiv(N, SCAN_CHUNK);  // blocks per scan array

    // workspace carve-up (64B-aligned chunks; sizes in bytes)
    char* wsp = (char*)d_ws;
    auto alloc = [&](size_t bytes) -> void* {
        void* p = (void*)wsp;
        wsp += ((bytes + 63) / 64) * 64;
        return p;
    };
    int* degs   = (int*)alloc((size_t)2 * N * 4);
    int* deg_r  = degs;
    int* deg_c  = degs + N;
    int* rptr   = (int*)alloc(((size_t)N + 1) * 4);
    int* cptr   = (int*)alloc(((size_t)N + 1) * 4);
    int2* adj   = (int2*)alloc((size_t)E * 8);
    int2* adjT  = (int2*)alloc((size_t)E * 8);
    unsigned short* xb   = (unsigned short*)alloc((size_t)N * DIM * 2);
    unsigned short* buf0 = (unsigned short*)alloc((size_t)N * DIM * 2);
    unsigned short* buf1 = (unsigned short*)alloc((size_t)N * DIM * 2);
    float* invs = (float*)alloc((size_t)2 * N * 4);
    float* inv_r = invs;
    float* inv_c = invs + N;
    float* cb   = (float*)alloc(64 * 4);
    float* W0c  = (float*)alloc(4096 * 4);
    int* part   = (int*)alloc((size_t)2 * G * 4);

    // slot arrays alias buf0/buf1 (each E ints = 6.4 MB <= 12.8 MB buffers;
    // buffers first written by SpMM, which runs after k_fill)
    int* slot_r = (int*)buf0;
    int* slot_c = (int*)buf1;

    hipMemsetAsync(degs, 0, (size_t)2 * N * sizeof(int), stream);

    k_degrees<<<idiv(E, 256), 256, 0, stream>>>(row, col, deg_r, deg_c, slot_r, slot_c, E);
    k_scan_blk<<<2 * G, 256, 0, stream>>>(deg_r, deg_c, part, N, G);
    k_scan_top<<<4, 1024, 0, stream>>>(part, G, bs_sd, b0_sd, bs_ds, b0_ds, cb, W0_sd, W0_ds, W0c);
    k_scan_fin<<<2 * G, 256, 0, stream>>>(deg_r, deg_c, part, rptr, cptr, inv_r, inv_c, N, G);
    k_fill<<<idiv(E, 256), 256, 0, stream>>>(row, col, rptr, cptr, slot_r, slot_c,
                                             inv_r, inv_c, adj, adjT, E);
    k_xcast<<<idiv(N * DIM / 4, 256), 256, 0, stream>>>(x, xb, N * DIM);

    int spmmGrid = idiv(N * 64, 256);  // one wave per row
    int gemmGrid = 2048;

    // hop 0: y0 = A x ; yt0 = A^T x
    k_spmm<<<spmmGrid, 256, 0, stream>>>(xb, buf0, rptr, adj, inv_r, N);
    k_spmm<<<spmmGrid, 256, 0, stream>>>(xb, buf1, cptr, adjT, inv_c, N);
    // out = cb + 0.5*(Ws_sd0 y0 + Ws_ds0 yt0)
    k_gemm2<true><<<gemmGrid, 256, 0, stream>>>(buf0, Ws_sd, buf1, Ws_ds, cb, out, 0.5f, N);
    // out += W0c x   (W0c = 0.5*(W0_sd + W0_ds), fp32 x)
    k_gemm_acc<<<gemmGrid, 256, 0, stream>>>(x, W0c, out, N);

    unsigned short* ycur = buf0;   // holds y_{i-1}
    unsigned short* yfree = buf1;  // consumed, reusable
    float sc = 1.f;
    for (int i = 1; i < 4; i++) {
        sc *= 0.5f;
        // y_i = A y_{i-1} -> yfree ;  yt_i = A^T y_i -> old ycur (dead)
        k_spmm<<<spmmGrid, 256, 0, stream>>>(ycur, yfree, rptr, adj, inv_r, N);
        k_spmm<<<spmmGrid, 256, 0, stream>>>(yfree, ycur, cptr, adjT, inv_c, N);
        // out += 0.5*sc*(Ws_sd[i] y_i + Ws_ds[i] yt_i)
        k_gemm2<false><<<gemmGrid, 256, 0, stream>>>(yfree, Ws_sd + (size_t)i * 4096,
                                                     ycur, Ws_ds + (size_t)i * 4096,
                                                     nullptr, out, 0.5f * sc, N);
        unsigned short* t = ycur; ycur = yfree; yfree = t;
    }
}

// Round 5
// 912.140 us; speedup vs baseline: 2.5247x; 1.6508x over previous
//
#include <hip/hip_runtime.h>
#include <hip/hip_bf16.h>

#define DIM 64
#define SCAN_CHUNK 2048

typedef __bf16 bf16v8 __attribute__((ext_vector_type(8)));
typedef float f32v4 __attribute__((ext_vector_type(4)));

static inline int idiv(int a, int b) { return (a + b - 1) / b; }

__device__ inline unsigned short f2b(float f) {
    __hip_bfloat16 h = __float2bfloat16(f);
    return *reinterpret_cast<unsigned short*>(&h);
}
__device__ inline float b2f(unsigned short u) {
    __hip_bfloat16 h;
    *reinterpret_cast<unsigned short*>(&h) = u;
    return __bfloat162float(h);
}

// ---------------- degrees + slot reservation ----------------
__global__ void k_degrees(const int* __restrict__ row, const int* __restrict__ col,
                          int* __restrict__ dr, int* __restrict__ dc,
                          int* __restrict__ slot_r, int* __restrict__ slot_c, int E) {
    int e = blockIdx.x * blockDim.x + threadIdx.x;
    if (e < E) {
        slot_r[e] = atomicAdd(&dr[row[e]], 1);
        slot_c[e] = atomicAdd(&dc[col[e]], 1);
    }
}

// ---------------- scan phase A: per-block partial sums ----------------
__global__ __launch_bounds__(256) void k_scan_blk(const int* __restrict__ deg_r,
                                                  const int* __restrict__ deg_c,
                                                  int* __restrict__ part, int n, int G) {
    int b = blockIdx.x;
    const int* deg = (b < G) ? deg_r : deg_c;
    int lb = (b < G) ? b : b - G;
    int base = lb * SCAN_CHUNK;
    int t = threadIdx.x;
    int s = 0;
    for (int i = t; i < SCAN_CHUNK; i += 256) {
        int g = base + i;
        if (g < n) s += deg[g];
    }
    __shared__ int red[256];
    red[t] = s;
    __syncthreads();
    for (int off = 128; off > 0; off >>= 1) {
        if (t < off) red[t] += red[t + off];
        __syncthreads();
    }
    if (t == 0) part[b] = red[0];
}

// ---------------- scan phase B: top scan (+ bias prep in spare block) ----------
__global__ __launch_bounds__(1024) void k_scan_top(int* __restrict__ part, int G,
        const float* __restrict__ bs_sd, const float* __restrict__ b0_sd,
        const float* __restrict__ bs_ds, const float* __restrict__ b0_ds,
        float* __restrict__ cb) {
    int t = threadIdx.x;
    if (blockIdx.x == 2) {
        if (t < 64) {
            float ssd = bs_sd[t] + b0_sd[t];
            float sds = bs_ds[t] + b0_ds[t];
            float sc = 1.f;
            for (int i = 1; i < 4; i++) {
                sc *= 0.5f;
                ssd += bs_sd[i * 64 + t] * sc;
                sds += bs_ds[i * 64 + t] * sc;
            }
            cb[t] = 0.5f * ssd + 0.5f * sds;  // ALPHA = 0.5
        }
        return;
    }
    int* p = part + ((blockIdx.x == 0) ? 0 : G);
    __shared__ int sums[1024];
    sums[t] = (t < G) ? p[t] : 0;
    __syncthreads();
    for (int off = 1; off < 1024; off <<= 1) {
        int v = (t >= off) ? sums[t - off] : 0;
        __syncthreads();
        sums[t] += v;
        __syncthreads();
    }
    if (t < G) p[t] = (t == 0) ? 0 : sums[t - 1];
}

// ---------------- scan phase C: finish — write ptr + inv ----------------
__global__ __launch_bounds__(256) void k_scan_fin(const int* __restrict__ deg_r,
                                                  const int* __restrict__ deg_c,
                                                  const int* __restrict__ part,
                                                  int* __restrict__ rptr, int* __restrict__ cptr,
                                                  float* __restrict__ inv_r, float* __restrict__ inv_c,
                                                  int n, int G) {
    int b = blockIdx.x;
    bool isr = (b < G);
    const int* deg = isr ? deg_r : deg_c;
    int* ptr = isr ? rptr : cptr;
    float* inv = isr ? inv_r : inv_c;
    int lb = isr ? b : b - G;
    int off = part[b];
    int base = lb * SCAN_CHUNK;
    int t = threadIdx.x;
    int start = base + t * 8;
    int v[8];
    int s = 0;
#pragma unroll
    for (int k = 0; k < 8; k++) {
        int g = start + k;
        int d = (g < n) ? deg[g] : 0;
        v[k] = d;
        s += d;
    }
    __shared__ int sums[256];
    sums[t] = s;
    __syncthreads();
    for (int o = 1; o < 256; o <<= 1) {
        int x = (t >= o) ? sums[t - o] : 0;
        __syncthreads();
        sums[t] += x;
        __syncthreads();
    }
    int run = off + ((t == 0) ? 0 : sums[t - 1]);
#pragma unroll
    for (int k = 0; k < 8; k++) {
        int g = start + k;
        if (g < n) {
            ptr[g] = run;
            inv[g] = (v[k] > 0) ? rsqrtf((float)v[k]) : 0.f;
            run += v[k];
        }
    }
    if (t == 255 && lb == G - 1) ptr[n] = run;  // grand total
}

// ---------------- CSR/CSC fill (atomic-free, packed idx+weight) ----------------
__global__ void k_fill(const int* __restrict__ row, const int* __restrict__ col,
                       const int* __restrict__ rptr, const int* __restrict__ cptr,
                       const int* __restrict__ slot_r, const int* __restrict__ slot_c,
                       const float* __restrict__ inv_r, const float* __restrict__ inv_c,
                       int2* __restrict__ adj, int2* __restrict__ adjT, int E) {
    int e = blockIdx.x * blockDim.x + threadIdx.x;
    if (e < E) {
        int r = row[e], c = col[e];
        adj[rptr[r] + slot_r[e]] = make_int2(c, __float_as_int(inv_c[c]));
        adjT[cptr[c] + slot_c[e]] = make_int2(r, __float_as_int(inv_r[r]));
    }
}

// ---------------- x -> bf16 cast ----------------
__global__ void k_xcast(const float* __restrict__ x, unsigned short* __restrict__ xb, int total) {
    int i = (blockIdx.x * blockDim.x + threadIdx.x) * 4;
    if (i < total) {
        float4 v = *reinterpret_cast<const float4*>(x + i);
        ushort4 o;
        o.x = f2b(v.x); o.y = f2b(v.y); o.z = f2b(v.z); o.w = f2b(v.w);
        *reinterpret_cast<ushort4*>(xb + i) = o;
    }
}

// ---------------- weight prep: bf16 cast with scale prefolded ----------------
// Wall layout: [0..3]=0.5*2^-i*Ws_sd[i], [4..7]=0.5*2^-i*Ws_ds[i], [8]=0.5*(W0_sd+W0_ds)
__global__ void k_wprep(const float* __restrict__ Ws_sd, const float* __restrict__ Ws_ds,
                        const float* __restrict__ W0_sd, const float* __restrict__ W0_ds,
                        unsigned short* __restrict__ Wall) {
    int i = blockIdx.x * blockDim.x + threadIdx.x;  // 9*4096 total
    if (i >= 9 * 4096) return;
    int m = i >> 12, e = i & 4095;
    float v;
    if (m < 4)      v = Ws_sd[m * 4096 + e] * (0.5f / (float)(1 << m));
    else if (m < 8) v = Ws_ds[(m - 4) * 4096 + e] * (0.5f / (float)(1 << (m - 4)));
    else            v = 0.5f * (W0_sd[e] + W0_ds[e]);
    Wall[i] = f2b(v);
}

// ---------------- SpMM (bf16 h, bf16 out, fp32 accum) ----------------
__global__ __launch_bounds__(256) void k_spmm(const unsigned short* __restrict__ h,
                                              unsigned short* __restrict__ out,
                                              const int* __restrict__ ptr,
                                              const int2* __restrict__ adj,
                                              const float* __restrict__ inv_self, int n) {
    int gw = (blockIdx.x * blockDim.x + threadIdx.x) >> 6;
    int lane = threadIdx.x & 63;
    if (gw >= n) return;
    int beg = ptr[gw], end = ptr[gw + 1];
    float acc = 0.f;
#pragma unroll 8
    for (int j = beg; j < end; j++) {
        int2 e = adj[j];
        acc = fmaf(__int_as_float(e.y), b2f(h[e.x * DIM + lane]), acc);
    }
    out[gw * DIM + lane] = f2b(inv_self[gw] * acc);
}

// ---------------- MFMA GEMM: out (=|+=) bias? + Wa ha + Wb hb [+ Wc hc] --------
// Scales are prefolded into the bf16 weights. One wave per 16-row tile.
// mfma_f32_16x16x32_bf16: A[m=lane&15][k=quad*8+j]; B-frag from W rows (W = B^T,
// row index o = lane&15); D: col(o)=lane&15, row(m)=quad*4+reg.
template <bool INIT, bool HAS_C>
__global__ __launch_bounds__(256) void k_gemm_mfma(
        const unsigned short* __restrict__ ha, const unsigned short* __restrict__ Wa,
        const unsigned short* __restrict__ hb, const unsigned short* __restrict__ Wb,
        const unsigned short* __restrict__ hc, const unsigned short* __restrict__ Wc,
        const float* __restrict__ cb, float* __restrict__ out, int n) {
    int lane = threadIdx.x & 63;
    int quad = lane >> 4;
    int l16 = lane & 15;
    int nmax = n - 1;
    int ntiles = n >> 4;  // full tiles; remainder handled by clamp+guard

    bf16v8 wa[4][2], wb[4][2], wc[HAS_C ? 4 : 1][2];
#pragma unroll
    for (int ot = 0; ot < 4; ot++)
#pragma unroll
        for (int kh = 0; kh < 2; kh++) {
            size_t off = (size_t)(ot * 16 + l16) * 64 + kh * 32 + quad * 8;
            wa[ot][kh] = *reinterpret_cast<const bf16v8*>(Wa + off);
            wb[ot][kh] = *reinterpret_cast<const bf16v8*>(Wb + off);
            if (HAS_C) wc[ot][kh] = *reinterpret_cast<const bf16v8*>(Wc + off);
        }
    float bias[4];
    if (INIT) {
#pragma unroll
        for (int ot = 0; ot < 4; ot++) bias[ot] = cb[ot * 16 + l16];
    }
    int tiles_all = (n + 15) >> 4;
    int wave = (blockIdx.x * blockDim.x + threadIdx.x) >> 6;
    int nw = (gridDim.x * blockDim.x) >> 6;
    for (int t = wave; t < tiles_all; t += nw) {
        int row0 = t << 4;
        int arow = min(row0 + l16, nmax);
        const bf16v8* pa = reinterpret_cast<const bf16v8*>(ha + (size_t)arow * 64 + quad * 8);
        const bf16v8* pb = reinterpret_cast<const bf16v8*>(hb + (size_t)arow * 64 + quad * 8);
        bf16v8 a0 = pa[0], a1 = pa[4];  // k 0..31 / 32..63
        bf16v8 b0 = pb[0], b1 = pb[4];
        bf16v8 c0, c1;
        if (HAS_C) {
            const bf16v8* pc = reinterpret_cast<const bf16v8*>(hc + (size_t)arow * 64 + quad * 8);
            c0 = pc[0]; c1 = pc[4];
        }
        f32v4 acc[4];
        if (INIT) {
#pragma unroll
            for (int ot = 0; ot < 4; ot++) {
                float b = bias[ot];
                acc[ot] = f32v4{b, b, b, b};
            }
        } else {
#pragma unroll
            for (int ot = 0; ot < 4; ot++)
#pragma unroll
                for (int r = 0; r < 4; r++)
                    acc[ot][r] = out[(size_t)min(row0 + quad * 4 + r, nmax) * 64 + ot * 16 + l16];
        }
#pragma unroll
        for (int ot = 0; ot < 4; ot++) {
            acc[ot] = __builtin_amdgcn_mfma_f32_16x16x32_bf16(a0, wa[ot][0], acc[ot], 0, 0, 0);
            acc[ot] = __builtin_amdgcn_mfma_f32_16x16x32_bf16(a1, wa[ot][1], acc[ot], 0, 0, 0);
            acc[ot] = __builtin_amdgcn_mfma_f32_16x16x32_bf16(b0, wb[ot][0], acc[ot], 0, 0, 0);
            acc[ot] = __builtin_amdgcn_mfma_f32_16x16x32_bf16(b1, wb[ot][1], acc[ot], 0, 0, 0);
            if (HAS_C) {
                acc[ot] = __builtin_amdgcn_mfma_f32_16x16x32_bf16(c0, wc[ot][0], acc[ot], 0, 0, 0);
                acc[ot] = __builtin_amdgcn_mfma_f32_16x16x32_bf16(c1, wc[ot][1], acc[ot], 0, 0, 0);
            }
        }
#pragma unroll
        for (int ot = 0; ot < 4; ot++)
#pragma unroll
            for (int r = 0; r < 4; r++) {
                int rr = row0 + quad * 4 + r;
                if (rr < n) out[(size_t)rr * 64 + ot * 16 + l16] = acc[ot][r];
            }
    }
    (void)ntiles;
}

extern "C" void kernel_launch(void* const* d_in, const int* in_sizes, int n_in,
                              void* d_out, int out_size, void* d_ws, size_t ws_size,
                              hipStream_t stream) {
    const float* x     = (const float*)d_in[0];
    const int*   ei    = (const int*)d_in[1];
    const float* Ws_sd = (const float*)d_in[2];
    const float* bs_sd = (const float*)d_in[3];
    const float* Ws_ds = (const float*)d_in[4];
    const float* bs_ds = (const float*)d_in[5];
    const float* W0_sd = (const float*)d_in[6];
    const float* b0_sd = (const float*)d_in[7];
    const float* W0_ds = (const float*)d_in[8];
    const float* b0_ds = (const float*)d_in[9];

    int N = in_sizes[0] / DIM;
    int E = in_sizes[1] / 2;
    const int* row = ei;
    const int* col = ei + E;
    float* out = (float*)d_out;

    int G = idiv(N, SCAN_CHUNK);  // blocks per scan array

    // workspace carve-up (64B-aligned chunks; sizes in bytes)
    char* wsp = (char*)d_ws;
    auto alloc = [&](size_t bytes) -> void* {
        void* p = (void*)wsp;
        wsp += ((bytes + 63) / 64) * 64;
        return p;
    };
    int* degs   = (int*)alloc((size_t)2 * N * 4);
    int* deg_r  = degs;
    int* deg_c  = degs + N;
    int* rptr   = (int*)alloc(((size_t)N + 1) * 4);
    int* cptr   = (int*)alloc(((size_t)N + 1) * 4);
    int2* adj   = (int2*)alloc((size_t)E * 8);
    int2* adjT  = (int2*)alloc((size_t)E * 8);
    unsigned short* xb   = (unsigned short*)alloc((size_t)N * DIM * 2);
    unsigned short* buf0 = (unsigned short*)alloc((size_t)N * DIM * 2);
    unsigned short* buf1 = (unsigned short*)alloc((size_t)N * DIM * 2);
    float* invs = (float*)alloc((size_t)2 * N * 4);
    float* inv_r = invs;
    float* inv_c = invs + N;
    float* cb   = (float*)alloc(64 * 4);
    unsigned short* Wall = (unsigned short*)alloc((size_t)9 * 4096 * 2);
    int* part   = (int*)alloc((size_t)2 * G * 4);

    // slot arrays alias buf0/buf1 (each E ints = 6.4 MB <= 12.8 MB buffers;
    // buffers first written by SpMM, which runs after k_fill)
    int* slot_r = (int*)buf0;
    int* slot_c = (int*)buf1;

    hipMemsetAsync(degs, 0, (size_t)2 * N * sizeof(int), stream);

    k_degrees<<<idiv(E, 256), 256, 0, stream>>>(row, col, deg_r, deg_c, slot_r, slot_c, E);
    k_scan_blk<<<2 * G, 256, 0, stream>>>(deg_r, deg_c, part, N, G);
    k_scan_top<<<3, 1024, 0, stream>>>(part, G, bs_sd, b0_sd, bs_ds, b0_ds, cb);
    k_scan_fin<<<2 * G, 256, 0, stream>>>(deg_r, deg_c, part, rptr, cptr, inv_r, inv_c, N, G);
    k_fill<<<idiv(E, 256), 256, 0, stream>>>(row, col, rptr, cptr, slot_r, slot_c,
                                             inv_r, inv_c, adj, adjT, E);
    k_xcast<<<idiv(N * DIM / 4, 256), 256, 0, stream>>>(x, xb, N * DIM);
    k_wprep<<<144, 256, 0, stream>>>(Ws_sd, Ws_ds, W0_sd, W0_ds, Wall);

    const unsigned short* Wsd[4] = {Wall, Wall + 4096, Wall + 8192, Wall + 12288};
    const unsigned short* Wds[4] = {Wall + 16384, Wall + 20480, Wall + 24576, Wall + 28672};
    const unsigned short* W0b = Wall + 32768;

    int spmmGrid = idiv(N * 64, 256);  // one wave per row
    int mfmaGrid = 1024;

    // hop 0: y0 = A x ; yt0 = A^T x ; out = cb + Wsd0 y0 + Wds0 yt0 + W0b x
    k_spmm<<<spmmGrid, 256, 0, stream>>>(xb, buf0, rptr, adj, inv_r, N);
    k_spmm<<<spmmGrid, 256, 0, stream>>>(xb, buf1, cptr, adjT, inv_c, N);
    k_gemm_mfma<true, true><<<mfmaGrid, 256, 0, stream>>>(buf0, Wsd[0], buf1, Wds[0],
                                                          xb, W0b, cb, out, N);

    unsigned short* ycur = buf0;   // holds y_{i-1}
    unsigned short* yfree = buf1;  // consumed, reusable
    for (int i = 1; i < 4; i++) {
        // y_i = A y_{i-1} -> yfree ;  yt_i = A^T y_i -> old ycur (dead)
        k_spmm<<<spmmGrid, 256, 0, stream>>>(ycur, yfree, rptr, adj, inv_r, N);
        k_spmm<<<spmmGrid, 256, 0, stream>>>(yfree, ycur, cptr, adjT, inv_c, N);
        k_gemm_mfma<false, false><<<mfmaGrid, 256, 0, stream>>>(yfree, Wsd[i], ycur, Wds[i],
                                                                nullptr, nullptr, nullptr, out, N);
        unsigned short* t = ycur; ycur = yfree; yfree = t;
    }
}